// Round 11
// baseline (248.081 us; speedup 1.0000x reference)
//
#include <hip/hip_runtime.h>

#define KK   128        // samples per ray
#define RPW  16         // rays per wave (wave-private group)
#define TPB  256        // 4 waves per block
#define GRIDB 1280      // 5 blocks/CU x 256 CU -> fully resident persistent grid

// borders = [z0, 0.5f*(z[i]+z[i-1]), z127]; expression text identical to R8/R9/R10
__device__ __forceinline__ float blerp(const float* __restrict__ Z, int c, float t)
{
    float zc = Z[c];
    float zm = Z[c > 0 ? c - 1 : 0];
    float zp = Z[c < KK - 1 ? c + 1 : KK - 1];
    float left  = (c == 0)      ? zc : 0.5f * (zc + zm);
    float right = (c == KK - 1) ? zc : 0.5f * (zp + zc);
    return left * (1.0f - t) + right * t;
}

__global__ __launch_bounds__(TPB, 4)
void nerf_sample_kernel(const float* __restrict__ Wg,
                        const float* __restrict__ Zg,
                        const float* __restrict__ Ug,
                        const float* __restrict__ Tg,
                        float* __restrict__ Og,
                        int ngroups, int stride)
{
    // per-wave 8KB cdf region; wave-private -> no s_barrier anywhere
    // (single-wavefront LDS accesses execute in program order on the DS pipe)
    __shared__ float S[4 * RPW * KK];   // 32 KB
    const int lane = threadIdx.x & 63;
    const int wvid = threadIdx.x >> 6;
    float* SW = S + wvid * (RPW * KK);

    const int r   = lane >> 2;          // ray slot 0..15 (build phases)
    const int q   = lane & 3;           // quarter: owns elements [32q, 32q+32)
    const int swz = (r & 7) << 3;       // 8-float-block XOR swizzle (keeps 16B align)
    float* Srow = SW + r * KK;

    const int g  = lane >> 4;           // phase-C ray subgroup 0..3
    const int ml = lane & 15;

    int grp = blockIdx.x * 4 + wvid;
    if (grp >= ngroups) return;

    // ---- load first group's raw W (per-lane contiguous 32 floats) ----
    float x[32];
    {
        const float* wp = Wg + (size_t)grp * (RPW * KK) + r * KK + q * 32;
        #pragma unroll
        for (int e = 0; e < 8; ++e) {
            float4 v = *(const float4*)(wp + 4 * e);
            x[4*e+0] = v.x; x[4*e+1] = v.y; x[4*e+2] = v.z; x[4*e+3] = v.w;
        }
    }

    const float EPSL = 1.0f - 1.8e-7f;
    const float EPSH = 1.0f + 1.8e-7f;

    while (true) {
        const size_t gbase = (size_t)grp * (RPW * KK);

        // ---- phase-C it=0 u/t prefetch: in flight during phases 2-4 ----
        const size_t pb0 = gbase + (size_t)g * KK + 4 * ml;
        float4 pu0 = *(const float4*)(Ug + pb0);
        float4 pu1 = *(const float4*)(Ug + pb0 + 64);
        float4 pt0 = *(const float4*)(Tg + pb0);
        float4 pt1 = *(const float4*)(Tg + pb0 + 64);

        // ---- w' = fl32(w + 1e-5f) ----
        #pragma unroll
        for (int j = 0; j < 32; ++j) x[j] += 1e-5f;

        // ---- tot: npyv model, EXACT R8 grouping, via 4-lane shuffles.
        // xk[c] = a[16k+c]; lane q holds chunks k=2q,2q+1 (x[c], x[16+c]).
        // A=xk+x(k+4) pairs live in lanes q^2; every add commutative-exact.
        float tot;
        {
            float C[16];
            #pragma unroll
            for (int c = 0; c < 16; ++c) {
                float a = x[c]      + __shfl_xor(x[c], 2);       // (x0+x4) etc.
                float b = x[16 + c] + __shfl_xor(x[16 + c], 2);  // (x1+x5) etc.
                C[c] = a + b;
            }
            float Sv[16];
            #pragma unroll
            for (int c = 0; c < 16; ++c) Sv[c] = C[c] + __shfl_xor(C[c], 1);
            float U[8];
            #pragma unroll
            for (int c = 0; c < 8; ++c) U[c] = Sv[c] + Sv[c + 8];
            float V4[4];
            #pragma unroll
            for (int c = 0; c < 4; ++c) V4[c] = U[c] + U[c + 4];
            tot = (V4[0] + V4[2]) + (V4[1] + V4[3]);
        }

        // ---- pdf: IEEE f32 divide ----
        #pragma unroll
        for (int j = 0; j < 32; ++j) x[j] = x[j] / tot;

        // ---- Brent-Kung scan in registers + cross-lane patch (R10 verbatim) ----
        #pragma unroll
        for (int m = 0; m < 16; ++m) x[2*m+1]  = x[2*m+1]  + x[2*m];
        #pragma unroll
        for (int m = 0; m < 8;  ++m) x[4*m+3]  = x[4*m+3]  + x[4*m+1];
        #pragma unroll
        for (int m = 0; m < 4;  ++m) x[8*m+7]  = x[8*m+7]  + x[8*m+3];
        #pragma unroll
        for (int m = 0; m < 2;  ++m) x[16*m+15] = x[16*m+15] + x[16*m+7];
        x[31] = x[31] + x[15];
        {
            float seg = x[31];
            float sA = __shfl_xor(seg, 1);
            float sB = __shfl_xor(seg, 2);
            float sC = __shfl_xor(sA, 2);
            float e0 = (q==0) ? seg : (q==1) ? sA : (q==2) ? sB : sC;
            float e1 = (q==0) ? sA  : (q==1) ? seg : (q==2) ? sC : sB;
            float e2 = (q==0) ? sB  : (q==1) ? sC  : (q==2) ? seg : sA;
            float s01   = e1 + e0;
            float s012  = e2 + s01;
            float s0123 = (seg + e2) + s01;
            if (q == 1) x[31] = s01;
            else if (q == 2) x[31] = s012;
            else if (q == 3) x[31] = s0123;
            float P = (q == 0) ? 0.0f : (q == 1) ? e0 : (q == 2) ? s01 : s012;

            x[15] = x[15] + P;
            x[7]  = x[7]  + P;  x[23] = x[23] + x[15];
            x[3]  = x[3]  + P;
            x[11] = x[11] + x[7]; x[19] = x[19] + x[15]; x[27] = x[27] + x[23];
            x[1]  = x[1]  + P;
            #pragma unroll
            for (int m = 1; m < 8; ++m)  x[4*m+1] = x[4*m+1] + x[4*m-1];
            x[0]  = x[0]  + P;
            #pragma unroll
            for (int m = 1; m < 16; ++m) x[2*m]   = x[2*m]   + x[2*m-1];
        }

        // ---- write cdf to wave-private LDS (8-float-block XOR swizzle) ----
        #pragma unroll
        for (int e = 0; e < 8; ++e)
            *(float4*)(Srow + ((32*q + 4*e) ^ swz)) =
                make_float4(x[4*e+0], x[4*e+1], x[4*e+2], x[4*e+3]);

        // wave-level fence: DS ops of one wave execute in order; just stop
        // the compiler from moving search reads above the writes.
        __builtin_amdgcn_sched_barrier(0);
        __builtin_amdgcn_wave_barrier();
        __builtin_amdgcn_sched_barrier(0);

        // ---- prefetch next group's raw W during the search ----
        const int  ngrp   = grp + stride;
        const bool nvalid = ngrp < ngroups;
        float xn[32];
        if (nvalid) {
            const float* wn = Wg + (size_t)ngrp * (RPW * KK) + r * KK + q * 32;
            #pragma unroll
            for (int e = 0; e < 8; ++e) {
                float4 v = *(const float4*)(wn + 4 * e);
                xn[4*e+0] = v.x; xn[4*e+1] = v.y; xn[4*e+2] = v.z; xn[4*e+3] = v.w;
            }
        }

        // ---- phase C: 4 iters x 4 rays; 16 lanes/ray, 8 hedged searches/lane ----
        for (int it = 0; it < 4; ++it) {
            const int rr  = 4 * it + g;
            const float* crow = SW + rr * KK;
            const int csw = (rr & 7) << 3;
            const size_t base = gbase + (size_t)rr * KK;

            float4 u0 = pu0, u1 = pu1, t0 = pt0, t1 = pt1;
            if (it < 3) {
                const size_t nb = gbase + (size_t)(4 * (it + 1) + g) * KK + 4 * ml;
                pu0 = *(const float4*)(Ug + nb);
                pu1 = *(const float4*)(Ug + nb + 64);
                pt0 = *(const float4*)(Tg + nb);
                pt1 = *(const float4*)(Tg + nb + 64);
            }

            float uu[8] = {u0.x, u0.y, u0.z, u0.w, u1.x, u1.y, u1.z, u1.w};
            float tv[8] = {t0.x, t0.y, t0.z, t0.w, t1.x, t1.y, t1.z, t1.w};
            float ul[8], uh[8];
            int h[8];
            #pragma unroll
            for (int i = 0; i < 8; ++i) {
                ul[i] = uu[i] * EPSL;
                uh[i] = uu[i] * EPSH;
                h[i] = 0;
            }
            #pragma unroll
            for (int s = 64; s >= 1; s >>= 1) {   // 8 independent chains
                #pragma unroll
                for (int i = 0; i < 8; ++i) {
                    float b = crow[(h[i] + s - 1) ^ csw];
                    if (b <= uh[i]) h[i] += s;
                }
            }

            const float* Z = Zg + base;
            float res[8];
            #pragma unroll
            for (int i = 0; i < 8; ++i) {
                const int hi = h[i];                  // #{cdf<=uh} capped at 127
                int li = hi;                          // l differs only in hedge window
                while (li > 0 && crow[(li - 1) ^ csw] > ul[i]) --li;
                res[i] = (li == hi) ? blerp(Z, hi, tv[i])
                                    : 0.5f * (blerp(Z, li, tv[i]) + blerp(Z, hi, tv[i]));
            }
            *(float4*)(Og + base + 4 * ml)      = make_float4(res[0], res[1], res[2], res[3]);
            *(float4*)(Og + base + 64 + 4 * ml) = make_float4(res[4], res[5], res[6], res[7]);
        }

        if (!nvalid) break;
        grp = ngrp;
        #pragma unroll
        for (int j = 0; j < 32; ++j) x[j] = xn[j];
    }
}

extern "C" void kernel_launch(void* const* d_in, const int* in_sizes, int n_in,
                              void* d_out, int out_size, void* d_ws, size_t ws_size,
                              hipStream_t stream)
{
    // inputs: 0=rays (unused), 1=weights, 2=z_samp, 3=u, 4=interval_interp
    const float* Wg = (const float*)d_in[1];
    const float* Zg = (const float*)d_in[2];
    const float* Ug = (const float*)d_in[3];
    const float* Tg = (const float*)d_in[4];
    float* Og = (float*)d_out;

    const int nrays   = in_sizes[1] / KK;     // 262144
    const int ngroups = nrays / RPW;          // 16384
    const int stride  = GRIDB * 4;            // total waves

    nerf_sample_kernel<<<dim3(GRIDB), dim3(TPB), 0, stream>>>(
        Wg, Zg, Ug, Tg, Og, ngroups, stride);
}

// Round 12
// 201.675 us; speedup vs baseline: 1.2301x; 1.2301x over previous
//
#include <hip/hip_runtime.h>

#define KK   128        // samples per ray
#define RPW  16         // rays per wave (wave-private group)
#define TPB  128        // 2 independent waves per block (dodges 16-wg/CU cap)

// borders = [z0, 0.5f*(z[i]+z[i-1]), z127]; expression text identical to R8-R11
__device__ __forceinline__ float blerp(const float* __restrict__ Z, int c, float t)
{
    float zc = Z[c];
    float zm = Z[c > 0 ? c - 1 : 0];
    float zp = Z[c < KK - 1 ? c + 1 : KK - 1];
    float left  = (c == 0)      ? zc : 0.5f * (zc + zm);
    float right = (c == KK - 1) ? zc : 0.5f * (zp + zc);
    return left * (1.0f - t) + right * t;
}

__global__ __launch_bounds__(TPB, 8)
void nerf_sample_kernel(const float* __restrict__ Wg,
                        const float* __restrict__ Zg,
                        const float* __restrict__ Ug,
                        const float* __restrict__ Tg,
                        float* __restrict__ Og)
{
    // per-wave 8KB cdf region; wave-private -> NO __syncthreads anywhere
    // (single-wave LDS accesses execute in program order on the DS pipe)
    __shared__ float S[2 * RPW * KK];   // 16 KB -> 10 blocks/CU by LDS
    const int lane = threadIdx.x & 63;
    const int wvid = threadIdx.x >> 6;
    float* SW = S + wvid * (RPW * KK);

    const int r   = lane >> 2;          // ray slot 0..15 (build phases)
    const int q   = lane & 3;           // quarter: owns elements [32q, 32q+32)
    const int swz = (r & 7) << 3;       // 8-float-block XOR swizzle (keeps 16B align)
    float* Srow = SW + r * KK;

    const int g  = lane >> 4;           // phase-C ray subgroup 0..3
    const int ml = lane & 15;

    const size_t grp   = (size_t)blockIdx.x * 2 + wvid;
    const size_t gbase = grp * (RPW * KK);

    // ---- load this wave's raw W (per-lane contiguous 32 floats) ----
    float x[32];
    {
        const float* wp = Wg + gbase + r * KK + q * 32;
        #pragma unroll
        for (int e = 0; e < 8; ++e) {
            float4 v = *(const float4*)(wp + 4 * e);
            x[4*e+0] = v.x; x[4*e+1] = v.y; x[4*e+2] = v.z; x[4*e+3] = v.w;
        }
    }

    // ---- phase-C it=0 u/t prefetch: in flight during the build phases ----
    const size_t pb0 = gbase + (size_t)g * KK + 4 * ml;
    float4 pu0 = *(const float4*)(Ug + pb0);
    float4 pu1 = *(const float4*)(Ug + pb0 + 64);
    float4 pt0 = *(const float4*)(Tg + pb0);
    float4 pt1 = *(const float4*)(Tg + pb0 + 64);

    // ---- w' = fl32(w + 1e-5f) ----
    #pragma unroll
    for (int j = 0; j < 32; ++j) x[j] += 1e-5f;

    // ---- tot: npyv model, EXACT R8 grouping, via 4-lane shuffles ----
    float tot;
    {
        float C[16];
        #pragma unroll
        for (int c = 0; c < 16; ++c) {
            float a = x[c]      + __shfl_xor(x[c], 2);
            float b = x[16 + c] + __shfl_xor(x[16 + c], 2);
            C[c] = a + b;
        }
        float Sv[16];
        #pragma unroll
        for (int c = 0; c < 16; ++c) Sv[c] = C[c] + __shfl_xor(C[c], 1);
        float U[8];
        #pragma unroll
        for (int c = 0; c < 8; ++c) U[c] = Sv[c] + Sv[c + 8];
        float V4[4];
        #pragma unroll
        for (int c = 0; c < 4; ++c) V4[c] = U[c] + U[c + 4];
        tot = (V4[0] + V4[2]) + (V4[1] + V4[3]);
    }

    // ---- pdf: IEEE f32 divide ----
    #pragma unroll
    for (int j = 0; j < 32; ++j) x[j] = x[j] / tot;

    // ---- Brent-Kung scan in registers + cross-lane patch (R10/R11 verbatim) ----
    #pragma unroll
    for (int m = 0; m < 16; ++m) x[2*m+1]  = x[2*m+1]  + x[2*m];
    #pragma unroll
    for (int m = 0; m < 8;  ++m) x[4*m+3]  = x[4*m+3]  + x[4*m+1];
    #pragma unroll
    for (int m = 0; m < 4;  ++m) x[8*m+7]  = x[8*m+7]  + x[8*m+3];
    #pragma unroll
    for (int m = 0; m < 2;  ++m) x[16*m+15] = x[16*m+15] + x[16*m+7];
    x[31] = x[31] + x[15];
    {
        float seg = x[31];
        float sA = __shfl_xor(seg, 1);
        float sB = __shfl_xor(seg, 2);
        float sC = __shfl_xor(sA, 2);
        float e0 = (q==0) ? seg : (q==1) ? sA : (q==2) ? sB : sC;
        float e1 = (q==0) ? sA  : (q==1) ? seg : (q==2) ? sC : sB;
        float e2 = (q==0) ? sB  : (q==1) ? sC  : (q==2) ? seg : sA;
        float s01   = e1 + e0;
        float s012  = e2 + s01;
        float s0123 = (seg + e2) + s01;
        if (q == 1) x[31] = s01;
        else if (q == 2) x[31] = s012;
        else if (q == 3) x[31] = s0123;
        float P = (q == 0) ? 0.0f : (q == 1) ? e0 : (q == 2) ? s01 : s012;

        x[15] = x[15] + P;
        x[7]  = x[7]  + P;  x[23] = x[23] + x[15];
        x[3]  = x[3]  + P;
        x[11] = x[11] + x[7]; x[19] = x[19] + x[15]; x[27] = x[27] + x[23];
        x[1]  = x[1]  + P;
        #pragma unroll
        for (int m = 1; m < 8; ++m)  x[4*m+1] = x[4*m+1] + x[4*m-1];
        x[0]  = x[0]  + P;
        #pragma unroll
        for (int m = 1; m < 16; ++m) x[2*m]   = x[2*m]   + x[2*m-1];
    }

    // ---- write cdf to wave-private LDS (8-float-block XOR swizzle) ----
    #pragma unroll
    for (int e = 0; e < 8; ++e)
        *(float4*)(Srow + ((32*q + 4*e) ^ swz)) =
            make_float4(x[4*e+0], x[4*e+1], x[4*e+2], x[4*e+3]);

    // wave-level fence only: stop the compiler reordering reads above writes
    __builtin_amdgcn_sched_barrier(0);
    __builtin_amdgcn_wave_barrier();
    __builtin_amdgcn_sched_barrier(0);

    // ---- phase C: 4 iters x 4 rays; 16 lanes/ray, 8 hedged searches/lane ----
    const float EPSL = 1.0f - 1.8e-7f;
    const float EPSH = 1.0f + 1.8e-7f;
    for (int it = 0; it < 4; ++it) {
        const int rr  = 4 * it + g;
        const float* crow = SW + rr * KK;
        const int csw = (rr & 7) << 3;
        const size_t base = gbase + (size_t)rr * KK;

        float4 u0 = pu0, u1 = pu1, t0 = pt0, t1 = pt1;
        if (it < 3) {
            const size_t nb = gbase + (size_t)(4 * (it + 1) + g) * KK + 4 * ml;
            pu0 = *(const float4*)(Ug + nb);
            pu1 = *(const float4*)(Ug + nb + 64);
            pt0 = *(const float4*)(Tg + nb);
            pt1 = *(const float4*)(Tg + nb + 64);
        }

        float uu[8] = {u0.x, u0.y, u0.z, u0.w, u1.x, u1.y, u1.z, u1.w};
        float tv[8] = {t0.x, t0.y, t0.z, t0.w, t1.x, t1.y, t1.z, t1.w};
        float ul[8], uh[8];
        int h[8];
        #pragma unroll
        for (int i = 0; i < 8; ++i) {
            ul[i] = uu[i] * EPSL;
            uh[i] = uu[i] * EPSH;
            h[i] = 0;
        }
        #pragma unroll
        for (int s = 64; s >= 1; s >>= 1) {   // 8 independent chains (ILP)
            #pragma unroll
            for (int i = 0; i < 8; ++i) {
                float b = crow[(h[i] + s - 1) ^ csw];
                if (b <= uh[i]) h[i] += s;
            }
        }

        const float* Z = Zg + base;
        float res[8];
        #pragma unroll
        for (int i = 0; i < 8; ++i) {
            const int hi = h[i];                  // #{cdf<=uh} capped at 127
            int li = hi;                          // l differs only in hedge window
            while (li > 0 && crow[(li - 1) ^ csw] > ul[i]) --li;
            res[i] = (li == hi) ? blerp(Z, hi, tv[i])
                                : 0.5f * (blerp(Z, li, tv[i]) + blerp(Z, hi, tv[i]));
        }
        *(float4*)(Og + base + 4 * ml)      = make_float4(res[0], res[1], res[2], res[3]);
        *(float4*)(Og + base + 64 + 4 * ml) = make_float4(res[4], res[5], res[6], res[7]);
    }
}

extern "C" void kernel_launch(void* const* d_in, const int* in_sizes, int n_in,
                              void* d_out, int out_size, void* d_ws, size_t ws_size,
                              hipStream_t stream)
{
    // inputs: 0=rays (unused), 1=weights, 2=z_samp, 3=u, 4=interval_interp
    const float* Wg = (const float*)d_in[1];
    const float* Zg = (const float*)d_in[2];
    const float* Ug = (const float*)d_in[3];
    const float* Tg = (const float*)d_in[4];
    float* Og = (float*)d_out;

    const int nrays  = in_sizes[1] / KK;        // 262144
    const int blocks = nrays / (2 * RPW);       // 8192 (2 waves x 16 rays each)

    nerf_sample_kernel<<<dim3(blocks), dim3(TPB), 0, stream>>>(Wg, Zg, Ug, Tg, Og);
}